// Round 1
// baseline (217.289 us; speedup 1.0000x reference)
//
#include <hip/hip_runtime.h>

// out[s,b,d] = x[s,b,d] + pe[s,d] + (any_p peaks[b,p]==s ? table[s,d] : 0)
// pe[s,2k]   = sin(s * exp(2k * -ln(1000)/D))
// pe[s,2k+1] = cos(s * exp(2k * -ln(1000)/D))
//
// S=256, B=2048, D=256, P=8. Memory-bound: 512MB read + 512MB write.

namespace {
constexpr int S      = 256;
constexpr int Bn     = 2048;
constexpr int D      = 256;
constexpr int P      = 8;
constexpr int D4     = D / 4;          // 64 float4 per row
constexpr int BTILE  = 128;            // batches per block
constexpr int NBT    = Bn / BTILE;     // 16 batch tiles per s-row
constexpr int THREADS = 256;
constexpr int ITERS  = BTILE * D4 / THREADS;  // 32 float4 per thread
}

__global__ __launch_bounds__(THREADS)
void pe_peak_kernel(const float* __restrict__ x,
                    const unsigned* __restrict__ pk,   // peak_positions, int32 or int64
                    const float* __restrict__ table,
                    float* __restrict__ out)
{
    __shared__ float4 s_pe[D4];          // pe[s, :]
    __shared__ float4 s_pt[D4];          // pe[s, :] + table[s, :]
    __shared__ unsigned char s_mask[BTILE];
    __shared__ int s_is64;

    const int t  = threadIdx.x;
    const int s  = blockIdx.x >> 4;              // / NBT (16)
    const int b0 = (blockIdx.x & (NBT - 1)) * BTILE;

    // --- detect int64 vs int32 peak buffer (values in [0,300): int64 => all
    //     odd u32 words are zero high-words; int32 => ~never all zero) -------
    if (t == 0) {
        unsigned o = 0;
        #pragma unroll
        for (int i = 0; i < 32; ++i) o |= pk[2 * i + 1];
        s_is64 = (o == 0) ? 1 : 0;
    }

    // --- pe[s,:] on the fly + table[s,:] staging (threads 0..63) -----------
    if (t < D4) {
        const float c = -6.907755278982137f / 256.0f;   // -ln(1000)/D
        float a0 = (float)s * expf((float)(4 * t) * c);       // pair k = 2t
        float a1 = (float)s * expf((float)(4 * t + 2) * c);   // pair k = 2t+1
        float4 pe4 = make_float4(sinf(a0), cosf(a0), sinf(a1), cosf(a1));
        float4 tb4 = reinterpret_cast<const float4*>(table)[s * D4 + t];
        s_pe[t] = pe4;
        s_pt[t] = make_float4(pe4.x + tb4.x, pe4.y + tb4.y,
                              pe4.z + tb4.z, pe4.w + tb4.w);
    }
    __syncthreads();

    // --- per-batch mask: does batch b have a peak at position s? -----------
    if (t < BTILE) {
        const int b = b0 + t;
        unsigned m = 0;
        if (s_is64) {
            #pragma unroll
            for (int p = 0; p < P; ++p) m |= (pk[(size_t)(b * P + p) * 2] == (unsigned)s);
        } else {
            #pragma unroll
            for (int p = 0; p < P; ++p) m |= (pk[b * P + p] == (unsigned)s);
        }
        s_mask[t] = (unsigned char)m;
    }
    __syncthreads();

    // --- stream the 128x256 tile, fully coalesced float4 -------------------
    const size_t base = ((size_t)s * Bn + b0) * D4;
    const float4* __restrict__ xr = reinterpret_cast<const float4*>(x) + base;
    float4* __restrict__ orow     = reinterpret_cast<float4*>(out) + base;

    #pragma unroll 8
    for (int j = 0; j < ITERS; ++j) {
        const int i  = j * THREADS + t;
        // i>>6 is wave-uniform (4 batch rows per 256-thread step), i&63 == lane
        const float4* __restrict__ addsrc = s_mask[i >> 6] ? s_pt : s_pe;
        const float4 a = addsrc[i & 63];
        float4 v = xr[i];
        v.x += a.x; v.y += a.y; v.z += a.z; v.w += a.w;
        orow[i] = v;
    }
}

extern "C" void kernel_launch(void* const* d_in, const int* in_sizes, int n_in,
                              void* d_out, int out_size, void* d_ws, size_t ws_size,
                              hipStream_t stream) {
    const float*    x     = (const float*)d_in[0];
    const unsigned* pk    = (const unsigned*)d_in[1];
    const float*    table = (const float*)d_in[2];
    float*          out   = (float*)d_out;

    pe_peak_kernel<<<dim3(S * NBT), dim3(THREADS), 0, stream>>>(x, pk, table, out);
}

// Round 2
// 201.079 us; speedup vs baseline: 1.0806x; 1.0806x over previous
//
#include <hip/hip_runtime.h>

// out[s,b,d] = x[s,b,d] + pe[s,d] + (any_p peaks[b,p]==s ? table[s,d] : 0)
// S=256, B=2048, D=256, P=8. Pure stream: 512MB read + 512MB write.
// Hot loop is LDS-free: pe/pe+table hoisted to registers (d-index is
// loop-invariant per thread), peak mask balloted into two u64 registers.

typedef float f32x4 __attribute__((ext_vector_type(4)));

namespace {
constexpr int S       = 256;
constexpr int Bn      = 2048;
constexpr int P       = 8;
constexpr int D4      = 64;            // 256 floats / 4
constexpr int BTILE   = 128;           // batches per block
constexpr int NBT     = Bn / BTILE;    // 16
constexpr int THREADS = 256;
constexpr int ITERS   = BTILE * D4 / THREADS;  // 32 float4 per thread
}

__global__ __launch_bounds__(THREADS)
void pe_peak_kernel(const float* __restrict__ x,
                    const unsigned* __restrict__ pk,   // int32 or int64 data
                    const float* __restrict__ table,
                    float* __restrict__ out)
{
    __shared__ f32x4 s_pe[D4];           // pe[s, :]
    __shared__ f32x4 s_pt[D4];           // pe[s, :] + table[s, :]
    __shared__ unsigned long long s_mb[2];  // 128 per-batch peak-hit bits
    __shared__ int s_is64;

    const int t  = threadIdx.x;
    const int s  = blockIdx.x >> 4;               // / NBT
    const int b0 = (blockIdx.x & (NBT - 1)) * BTILE;

    // --- int64 vs int32 width detect: values < 300, so int64 => all high
    //     words zero; int32 => 32 consecutive zeros is impossible in practice.
    {
        unsigned hw = (t < 32) ? pk[2 * t + 1] : 0u;
        unsigned long long nz = __ballot(hw != 0u);
        if (t == 0) s_is64 = (nz == 0ull) ? 1 : 0;
    }

    // --- pe[s,:] on the fly + pe+table staged once (threads 0..63) ---------
    if (t < D4) {
        const float c = -6.907755278982137f / 256.0f;   // -ln(1000)/D
        float a0 = (float)s * expf((float)(4 * t) * c);       // pair k=2t
        float a1 = (float)s * expf((float)(4 * t + 2) * c);   // pair k=2t+1
        f32x4 pe4;
        pe4.x = sinf(a0); pe4.y = cosf(a0);
        pe4.z = sinf(a1); pe4.w = cosf(a1);
        f32x4 tb4 = reinterpret_cast<const f32x4*>(table)[s * D4 + t];
        s_pe[t] = pe4;
        s_pt[t] = pe4 + tb4;
    }
    __syncthreads();

    // --- per-batch "peak at s" bit, balloted into 2x u64 -------------------
    bool m = false;
    if (t < BTILE) {
        const int b = b0 + t;
        if (s_is64) {
            #pragma unroll
            for (int p = 0; p < P; ++p) m |= (pk[(size_t)(b * P + p) * 2] == (unsigned)s);
        } else {
            #pragma unroll
            for (int p = 0; p < P; ++p) m |= (pk[b * P + p] == (unsigned)s);
        }
    }
    {
        unsigned long long bal = __ballot(m);
        if (t < 128 && (t & 63) == 0) s_mb[t >> 6] = bal;
    }
    __syncthreads();

    // --- hoist everything the hot loop needs into registers ----------------
    const int lane = t & 63;     // d4 index (loop-invariant)
    const int w    = t >> 6;     // batch-row offset within each 4-row slab
    const f32x4 pe4 = s_pe[lane];
    const f32x4 pt4 = s_pt[lane];
    const unsigned long long mb0 = s_mb[0];
    const unsigned long long mb1 = s_mb[1];

    // --- stream 128x256 floats, batched 8 loads -> 8 add+stores ------------
    const size_t base = ((size_t)s * Bn + b0) * D4;
    const f32x4* __restrict__ xr = reinterpret_cast<const f32x4*>(x) + base;
    f32x4* __restrict__ orow     = reinterpret_cast<f32x4*>(out) + base;

    #pragma unroll
    for (int j0 = 0; j0 < ITERS; j0 += 8) {
        f32x4 v[8];
        #pragma unroll
        for (int u = 0; u < 8; ++u)
            v[u] = __builtin_nontemporal_load(xr + (size_t)(j0 + u) * THREADS + t);
        #pragma unroll
        for (int u = 0; u < 8; ++u) {
            const int j = j0 + u;
            const unsigned long long mb = (j < 16) ? mb0 : mb1;   // compile-time select
            const bool hit = (mb >> ((4 * j + w) & 63)) & 1ull;
            const f32x4 a = hit ? pt4 : pe4;
            __builtin_nontemporal_store(v[u] + a, orow + (size_t)j * THREADS + t);
        }
    }
}

extern "C" void kernel_launch(void* const* d_in, const int* in_sizes, int n_in,
                              void* d_out, int out_size, void* d_ws, size_t ws_size,
                              hipStream_t stream) {
    const float*    x     = (const float*)d_in[0];
    const unsigned* pk    = (const unsigned*)d_in[1];
    const float*    table = (const float*)d_in[2];
    float*          out   = (float*)d_out;

    pe_peak_kernel<<<dim3(S * NBT), dim3(THREADS), 0, stream>>>(x, pk, table, out);
}